// Round 1
// baseline (1212.741 us; speedup 1.0000x reference)
//
#include <hip/hip_runtime.h>
#include <hip/hip_bf16.h>

using bf16 = __hip_bfloat16;
typedef __attribute__((ext_vector_type(4))) float f4;
typedef __attribute__((ext_vector_type(8))) short s8v;
typedef __attribute__((ext_vector_type(4))) short s4v;
typedef __attribute__((ext_vector_type(4))) unsigned int u4v;

__device__ __forceinline__ short f2bf(float x) {
  bf16 h = __float2bfloat16(x);
  return *reinterpret_cast<short*>(&h);
}

// ------------------------------------------------------------------
// cache_k [b][kv][p][d] f32 -> kfull [b][kv][p][d] bf16 (p < 1024)
__global__ __launch_bounds__(256) void cvt_cache_k(const float* __restrict__ src,
                                                   bf16* __restrict__ dst) {
  size_t e = ((size_t)blockIdx.x * 256 + threadIdx.x) << 2;   // 4 elems/thread
  f4 v = *(const f4*)(src + e);
  unsigned d = (unsigned)(e & 127u), p = (unsigned)((e >> 7) & 1023u), bk = (unsigned)(e >> 17);
  s4v r = { f2bf(v[0]), f2bf(v[1]), f2bf(v[2]), f2bf(v[3]) };
  *(s4v*)(dst + (((size_t)bk * 2048 + p) << 7) + d) = r;
}

// cache_v [b][kv][p][d] f32 -> vt [b][kv][d][p] bf16 (transposed, p < 1024)
__global__ __launch_bounds__(256) void cvt_cache_v(const float* __restrict__ src,
                                                   bf16* __restrict__ dst) {
  size_t e = ((size_t)blockIdx.x * 256 + threadIdx.x) << 2;   // output-linear
  unsigned p = (unsigned)(e & 1023u), d = (unsigned)((e >> 10) & 127u), bk = (unsigned)(e >> 17);
  const float* s = src + (((size_t)bk * 1024 + p) << 7) + d;
  s4v r = { f2bf(s[0]), f2bf(s[128]), f2bf(s[256]), f2bf(s[384]) };
  *(s4v*)(dst + (((size_t)bk * 128 + d) << 11) + p) = r;
}

// ------------------------------------------------------------------
// in-place RoPE on bf16 buffer laid out [hh][sstride][128]; rows soff+s
__global__ __launch_bounds__(256) void rope_kernel(bf16* __restrict__ buf,
                                                   const float* __restrict__ fc,
                                                   const float* __restrict__ fs,
                                                   int sstride, int soff) {
  size_t t = (size_t)blockIdx.x * 256 + threadIdx.x;
  unsigned ip = (unsigned)(t & 63u);
  unsigned s  = (unsigned)((t >> 6) & 1023u);
  unsigned hh = (unsigned)(t >> 16);
  size_t base = ((size_t)hh * sstride + soff + s) * 128 + 2 * ip;
  unsigned u = *(unsigned*)(buf + base);
  float xr = __uint_as_float(u << 16);
  float xi = __uint_as_float(u & 0xffff0000u);
  float c = fc[s * 64 + ip], sn = fs[s * 64 + ip];
  unsigned short r0 = (unsigned short)f2bf(xr * c - xi * sn);
  unsigned short r1 = (unsigned short)f2bf(xr * sn + xi * c);
  *(unsigned*)(buf + base) = (unsigned)r0 | ((unsigned)r1 << 16);
}

// ------------------------------------------------------------------
// GEMM: C[m,n] = sum_k A[m,k] * B[n,k]   (B stored [N][K], fp32)
// A is fp32 or bf16; staged to LDS as bf16 (cvt in regs). 128x128 tile, BK=32.
#define MODE_Q  0
#define MODE_K  1
#define MODE_V  2
#define MODE_OUT 3

template <typename TA, int MODE>
__global__ __launch_bounds__(256) void gemm_bt(const TA* __restrict__ A,
                                               const float* __restrict__ B,
                                               void* __restrict__ outp,
                                               int M, int N, int K, float scale) {
  __shared__ alignas(16) bf16 As[2][128][40];   // +8 pad: 2-way banks (free)
  __shared__ alignas(16) bf16 Bs[2][128][40];

  const int tid = threadIdx.x;
  const int bm = blockIdx.x, bn = blockIdx.y;
  const int srow = tid >> 1;
  const int scol = (tid & 1) << 4;

  const TA* aptr = A + (size_t)(bm * 128 + srow) * K + scol;
  const float* bptr = B + (size_t)(bn * 128 + srow) * K + scol;

  const int lane = tid & 63;
  const int wid = tid >> 6;
  const int wr = (wid >> 1) << 6;
  const int wc = (wid & 1) << 6;
  const int fr = lane & 15;
  const int fk = (lane >> 4) << 3;
  const int rg = (lane >> 4) << 2;

  f4 acc[4][4] = {};

  f4 raf[4]; u4v rab[2]; f4 rbf[4];

  auto loadA = [&](int kt) {
    if constexpr (sizeof(TA) == 4) {
      const f4* p = (const f4*)(aptr + (size_t)kt * 32);
      raf[0] = p[0]; raf[1] = p[1]; raf[2] = p[2]; raf[3] = p[3];
    } else {
      const u4v* p = (const u4v*)(aptr + (size_t)kt * 32);
      rab[0] = p[0]; rab[1] = p[1];
    }
  };
  auto loadB = [&](int kt) {
    const f4* p = (const f4*)(bptr + (size_t)kt * 32);
    rbf[0] = p[0]; rbf[1] = p[1]; rbf[2] = p[2]; rbf[3] = p[3];
  };
  auto storeA = [&](int buf) {
    bf16* d = &As[buf][srow][scol];
    if constexpr (sizeof(TA) == 4) {
      s8v lo = { f2bf(raf[0][0]), f2bf(raf[0][1]), f2bf(raf[0][2]), f2bf(raf[0][3]),
                 f2bf(raf[1][0]), f2bf(raf[1][1]), f2bf(raf[1][2]), f2bf(raf[1][3]) };
      s8v hi = { f2bf(raf[2][0]), f2bf(raf[2][1]), f2bf(raf[2][2]), f2bf(raf[2][3]),
                 f2bf(raf[3][0]), f2bf(raf[3][1]), f2bf(raf[3][2]), f2bf(raf[3][3]) };
      *(s8v*)d = lo;
      *(s8v*)(d + 8) = hi;
    } else {
      *(u4v*)d = rab[0];
      *(u4v*)(d + 8) = rab[1];
    }
  };
  auto storeB = [&](int buf) {
    bf16* d = &Bs[buf][srow][scol];
    s8v lo = { f2bf(rbf[0][0]), f2bf(rbf[0][1]), f2bf(rbf[0][2]), f2bf(rbf[0][3]),
               f2bf(rbf[1][0]), f2bf(rbf[1][1]), f2bf(rbf[1][2]), f2bf(rbf[1][3]) };
    s8v hi = { f2bf(rbf[2][0]), f2bf(rbf[2][1]), f2bf(rbf[2][2]), f2bf(rbf[2][3]),
               f2bf(rbf[3][0]), f2bf(rbf[3][1]), f2bf(rbf[3][2]), f2bf(rbf[3][3]) };
    *(s8v*)d = lo;
    *(s8v*)(d + 8) = hi;
  };

  loadA(0); loadB(0);
  storeA(0); storeB(0);
  __syncthreads();

  const int nk = K >> 5;
  for (int kt = 0; kt < nk; ++kt) {
    const int cur = kt & 1;
    if (kt + 1 < nk) { loadA(kt + 1); loadB(kt + 1); }

    s8v af[4], bfv[4];
#pragma unroll
    for (int m = 0; m < 4; ++m) af[m] = *(const s8v*)&As[cur][wr + m * 16 + fr][fk];
#pragma unroll
    for (int n = 0; n < 4; ++n) bfv[n] = *(const s8v*)&Bs[cur][wc + n * 16 + fr][fk];
#pragma unroll
    for (int m = 0; m < 4; ++m)
#pragma unroll
      for (int n = 0; n < 4; ++n)
        acc[m][n] = __builtin_amdgcn_mfma_f32_16x16x32_bf16(af[m], bfv[n], acc[m][n], 0, 0, 0);

    __syncthreads();
    if (kt + 1 < nk) {
      storeA(cur ^ 1); storeB(cur ^ 1);
      __syncthreads();
    }
  }

  // epilogue: C row = token t (b = t>>10, s = t&1023); col n
#pragma unroll
  for (int m = 0; m < 4; ++m) {
    const int gr0 = bm * 128 + wr + m * 16 + rg;   // rows gr0..gr0+3
#pragma unroll
    for (int n = 0; n < 4; ++n) {
      const int gcol = bn * 128 + wc + n * 16 + fr;
      if constexpr (MODE == MODE_V) {
        const int b = gr0 >> 10, s0 = gr0 & 1023;
        const int hv = gcol >> 7, d = gcol & 127;
        s4v r = { f2bf(acc[m][n][0]), f2bf(acc[m][n][1]),
                  f2bf(acc[m][n][2]), f2bf(acc[m][n][3]) };
        *(s4v*)((bf16*)outp + (((size_t)b * 8 + hv) * 128 + d) * 2048 + 1024 + s0) = r;
      } else {
#pragma unroll
        for (int j = 0; j < 4; ++j) {
          const int gr = gr0 + j;
          const float v = acc[m][n][j] * scale;
          if constexpr (MODE == MODE_OUT) {
            ((float*)outp)[(size_t)gr * N + gcol] = v;
          } else if constexpr (MODE == MODE_Q) {
            const int b = gr >> 10, s0 = gr & 1023;
            const int h = gcol >> 7, d = gcol & 127;
            ((bf16*)outp)[((((size_t)b * 32 + h) << 10) + s0) * 128 + d] = __float2bfloat16(v);
          } else {  // MODE_K
            const int b = gr >> 10, s0 = gr & 1023;
            const int h = gcol >> 7, d = gcol & 127;
            ((bf16*)outp)[(((size_t)b * 8 + h) * 2048 + 1024 + s0) * 128 + d] = __float2bfloat16(v);
          }
        }
      }
    }
  }
}

// ------------------------------------------------------------------
// Flash attention, no mask. Q pre-scaled by 1/sqrt(128) (folded into Q GEMM).
// grid: (16 q-blocks, 128 b*h). 256 threads = 4 waves x 16 q-rows each.
__global__ __launch_bounds__(256) void attn_kernel(const bf16* __restrict__ Q,
                                                   const bf16* __restrict__ Kf,
                                                   const bf16* __restrict__ Vt,
                                                   bf16* __restrict__ O) {
  __shared__ alignas(16) bf16 Ks[64][136];   // keys x dim, +8 pad
  __shared__ alignas(16) bf16 Vs[128][72];   // dim  x keys, +8 pad
  __shared__ alignas(16) bf16 Ps[4][16][72]; // per-wave P tile

  const int tid = threadIdx.x;
  const int lane = tid & 63;
  const int w = tid >> 6;
  const int fr = lane & 15;
  const int fk = (lane >> 4) << 3;
  const int rg = (lane >> 4) << 2;

  const int qb = blockIdx.x;          // 0..15
  const int bh = blockIdx.y;          // 0..127
  const int b = bh >> 5, h = bh & 31;
  const int kv = h >> 2;

  const size_t qbase = (((size_t)b * 32 + h) << 10) * 128;
  const size_t kbase = (((size_t)b * 8 + kv) * 2048) * 128;
  const size_t vbase = (((size_t)b * 8 + kv) * 128) * 2048;

  const int qrow = qb * 64 + w * 16 + fr;
  s8v qa[4];
#pragma unroll
  for (int ks = 0; ks < 4; ++ks)
    qa[ks] = *(const s8v*)&Q[qbase + (size_t)qrow * 128 + ks * 32 + fk];

  f4 acco[8] = {};
  float mrun[4], lrun[4];
#pragma unroll
  for (int j = 0; j < 4; ++j) { mrun[j] = -1e30f; lrun[j] = 0.0f; }

  const int krow = tid >> 2, kcol = (tid & 3) << 5;   // 64x128 tile
  const int vrow = tid >> 1, vcol = (tid & 1) << 5;   // 128x64 tile

  for (int kb = 0; kb < 32; ++kb) {
    // stage K and Vt tiles
    const u4v* kg = (const u4v*)&Kf[kbase + (size_t)(kb * 64 + krow) * 128 + kcol];
    u4v k0 = kg[0], k1 = kg[1], k2 = kg[2], k3 = kg[3];
    const u4v* vg = (const u4v*)&Vt[vbase + (size_t)vrow * 2048 + kb * 64 + vcol];
    u4v v0 = vg[0], v1 = vg[1], v2 = vg[2], v3 = vg[3];
    *(u4v*)&Ks[krow][kcol +  0] = k0;
    *(u4v*)&Ks[krow][kcol +  8] = k1;
    *(u4v*)&Ks[krow][kcol + 16] = k2;
    *(u4v*)&Ks[krow][kcol + 24] = k3;
    *(u4v*)&Vs[vrow][vcol +  0] = v0;
    *(u4v*)&Vs[vrow][vcol +  8] = v1;
    *(u4v*)&Vs[vrow][vcol + 16] = v2;
    *(u4v*)&Vs[vrow][vcol + 24] = v3;
    __syncthreads();

    // S = Q K^T  (16 q-rows x 64 keys per wave)
    f4 sc[4];
#pragma unroll
    for (int n = 0; n < 4; ++n) {
      f4 a = {0.f, 0.f, 0.f, 0.f};
#pragma unroll
      for (int ks = 0; ks < 4; ++ks) {
        s8v kfv = *(const s8v*)&Ks[n * 16 + fr][ks * 32 + fk];
        a = __builtin_amdgcn_mfma_f32_16x16x32_bf16(qa[ks], kfv, a, 0, 0, 0);
      }
      sc[n] = a;
    }

    // online softmax; row r = rg + j lives in the 16-lane group sharing lane>>4
    float pm[4];
#pragma unroll
    for (int j = 0; j < 4; ++j)
      pm[j] = fmaxf(fmaxf(sc[0][j], sc[1][j]), fmaxf(sc[2][j], sc[3][j]));
#pragma unroll
    for (int j = 0; j < 4; ++j) {
      pm[j] = fmaxf(pm[j], __shfl_xor(pm[j], 1));
      pm[j] = fmaxf(pm[j], __shfl_xor(pm[j], 2));
      pm[j] = fmaxf(pm[j], __shfl_xor(pm[j], 4));
      pm[j] = fmaxf(pm[j], __shfl_xor(pm[j], 8));
    }
    float corr[4], rs[4];
#pragma unroll
    for (int j = 0; j < 4; ++j) {
      const float mn = fmaxf(mrun[j], pm[j]);
      corr[j] = __expf(mrun[j] - mn);
      mrun[j] = mn;
      float s0 = 0.f;
#pragma unroll
      for (int n = 0; n < 4; ++n) {
        const float p = __expf(sc[n][j] - mn);
        sc[n][j] = p;
        s0 += p;
      }
      rs[j] = s0;
    }
#pragma unroll
    for (int j = 0; j < 4; ++j) {
      rs[j] += __shfl_xor(rs[j], 1);
      rs[j] += __shfl_xor(rs[j], 2);
      rs[j] += __shfl_xor(rs[j], 4);
      rs[j] += __shfl_xor(rs[j], 8);
      lrun[j] = lrun[j] * corr[j] + rs[j];
    }
#pragma unroll
    for (int nt = 0; nt < 8; ++nt)
#pragma unroll
      for (int j = 0; j < 4; ++j) acco[nt][j] *= corr[j];

    // P -> per-wave LDS (wave-local; lgkmcnt(0) is the only fence needed)
#pragma unroll
    for (int n = 0; n < 4; ++n)
#pragma unroll
      for (int j = 0; j < 4; ++j)
        Ps[w][rg + j][fr + n * 16] = __float2bfloat16(sc[n][j]);
    asm volatile("s_waitcnt lgkmcnt(0)" ::: "memory");

    // O += P V  (A = P rows, B-frag = rows of Vt tile)
#pragma unroll
    for (int ks2 = 0; ks2 < 2; ++ks2) {
      s8v pf = *(const s8v*)&Ps[w][fr][ks2 * 32 + fk];
#pragma unroll
      for (int nt = 0; nt < 8; ++nt) {
        s8v vf = *(const s8v*)&Vs[nt * 16 + fr][ks2 * 32 + fk];
        acco[nt] = __builtin_amdgcn_mfma_f32_16x16x32_bf16(pf, vf, acco[nt], 0, 0, 0);
      }
    }
    __syncthreads();
  }

  // normalize + write attn[t][h*128+d]
#pragma unroll
  for (int nt = 0; nt < 8; ++nt)
#pragma unroll
    for (int j = 0; j < 4; ++j) {
      const int r = qb * 64 + w * 16 + rg + j;
      const int dcol = nt * 16 + fr;
      const float v = acco[nt][j] / lrun[j];
      O[((size_t)b * 1024 + r) * 4096 + h * 128 + dcol] = __float2bfloat16(v);
    }
}

// ------------------------------------------------------------------
extern "C" void kernel_launch(void* const* d_in, const int* in_sizes, int n_in,
                              void* d_out, int out_size, void* d_ws, size_t ws_size,
                              hipStream_t stream) {
  const float* x  = (const float*)d_in[0];
  const float* fc = (const float*)d_in[1];
  const float* fs = (const float*)d_in[2];
  const float* ck = (const float*)d_in[3];
  const float* cv = (const float*)d_in[4];
  const float* wq = (const float*)d_in[5];
  const float* wk = (const float*)d_in[6];
  const float* wv = (const float*)d_in[7];
  const float* wo = (const float*)d_in[8];
  float* out = (float*)d_out;

  char* ws = (char*)d_ws;
  bf16* qr    = (bf16*)(ws);                     // [4][32][1024][128]  32 MiB
  bf16* kfull = (bf16*)(ws + (32u << 20));       // [4][8][2048][128]   16 MiB
  bf16* vt    = (bf16*)(ws + (48u << 20));       // [4][8][128][2048]   16 MiB
  bf16* attn  = (bf16*)(ws + (64u << 20));       // [4096][4096]        32 MiB

  cvt_cache_k<<<4096, 256, 0, stream>>>(ck, kfull);
  cvt_cache_v<<<4096, 256, 0, stream>>>(cv, vt);

  gemm_bt<float, MODE_Q><<<dim3(32, 32), 256, 0, stream>>>(
      x, wq, qr, 4096, 4096, 4096, 0.08838834764831845f);
  gemm_bt<float, MODE_K><<<dim3(32, 8), 256, 0, stream>>>(
      x, wk, kfull, 4096, 1024, 4096, 1.0f);
  gemm_bt<float, MODE_V><<<dim3(32, 8), 256, 0, stream>>>(
      x, wv, vt, 4096, 1024, 4096, 1.0f);

  rope_kernel<<<32768, 256, 0, stream>>>(qr, fc, fs, 1024, 0);
  rope_kernel<<<8192, 256, 0, stream>>>(kfull, fc, fs, 2048, 1024);

  attn_kernel<<<dim3(16, 128), 256, 0, stream>>>(qr, kfull, vt, attn);

  gemm_bt<bf16, MODE_OUT><<<dim3(32, 32), 256, 0, stream>>>(
      attn, wo, out, 4096, 4096, 4096, 1.0f);
}

// Round 2
// 901.070 us; speedup vs baseline: 1.3459x; 1.3459x over previous
//
#include <hip/hip_runtime.h>
#include <hip/hip_bf16.h>

using bf16 = __hip_bfloat16;
typedef __attribute__((ext_vector_type(4))) float f4;
typedef __attribute__((ext_vector_type(8))) short s8v;
typedef __attribute__((ext_vector_type(4))) short s4v;
typedef __attribute__((ext_vector_type(4))) unsigned int u4v;
typedef unsigned int u32;

__device__ __forceinline__ short f2bf(float x) {
  bf16 h = __float2bfloat16(x);
  return *reinterpret_cast<short*>(&h);
}

__device__ __forceinline__ void gload16(const bf16* g, bf16* l) {
  __builtin_amdgcn_global_load_lds(
      (const __attribute__((address_space(1))) u32*)g,
      (__attribute__((address_space(3))) u32*)l, 16, 0, 0);
}

// ------------------------------------------------------------------
// generic fp32 -> bf16, 8 elems/thread; n must be multiple of 2048
__global__ __launch_bounds__(256) void cvt_bf16(const float* __restrict__ src,
                                                bf16* __restrict__ dst) {
  size_t e = ((size_t)blockIdx.x * 256 + threadIdx.x) << 3;
  f4 a = *(const f4*)(src + e);
  f4 b = *(const f4*)(src + e + 4);
  s8v r = { f2bf(a[0]), f2bf(a[1]), f2bf(a[2]), f2bf(a[3]),
            f2bf(b[0]), f2bf(b[1]), f2bf(b[2]), f2bf(b[3]) };
  *(s8v*)(dst + e) = r;
}

// cache_k [b][kv][p][d] f32 -> kfull [b][kv][p][d] bf16 (p < 1024)
__global__ __launch_bounds__(256) void cvt_cache_k(const float* __restrict__ src,
                                                   bf16* __restrict__ dst) {
  size_t e = ((size_t)blockIdx.x * 256 + threadIdx.x) << 2;
  f4 v = *(const f4*)(src + e);
  unsigned d = (unsigned)(e & 127u), p = (unsigned)((e >> 7) & 1023u), bk = (unsigned)(e >> 17);
  s4v r = { f2bf(v[0]), f2bf(v[1]), f2bf(v[2]), f2bf(v[3]) };
  *(s4v*)(dst + (((size_t)bk * 2048 + p) << 7) + d) = r;
}

// cache_v [b][kv][p][d] f32 -> vt [b][kv][d][p] bf16 (transposed, p < 1024)
__global__ __launch_bounds__(256) void cvt_cache_v(const float* __restrict__ src,
                                                   bf16* __restrict__ dst) {
  size_t e = ((size_t)blockIdx.x * 256 + threadIdx.x) << 2;
  unsigned p = (unsigned)(e & 1023u), d = (unsigned)((e >> 10) & 127u), bk = (unsigned)(e >> 17);
  const float* s = src + (((size_t)bk * 1024 + p) << 7) + d;
  s4v r = { f2bf(s[0]), f2bf(s[128]), f2bf(s[256]), f2bf(s[384]) };
  *(s4v*)(dst + (((size_t)bk * 128 + d) << 11) + p) = r;
}

// ------------------------------------------------------------------
// in-place RoPE on bf16 buffer laid out [hh][sstride][128]; rows soff+s
__global__ __launch_bounds__(256) void rope_kernel(bf16* __restrict__ buf,
                                                   const float* __restrict__ fc,
                                                   const float* __restrict__ fs,
                                                   int sstride, int soff) {
  size_t t = (size_t)blockIdx.x * 256 + threadIdx.x;
  unsigned ip = (unsigned)(t & 63u);
  unsigned s  = (unsigned)((t >> 6) & 1023u);
  unsigned hh = (unsigned)(t >> 16);
  size_t base = ((size_t)hh * sstride + soff + s) * 128 + 2 * ip;
  unsigned u = *(unsigned*)(buf + base);
  float xr = __uint_as_float(u << 16);
  float xi = __uint_as_float(u & 0xffff0000u);
  float c = fc[s * 64 + ip], sn = fs[s * 64 + ip];
  unsigned short r0 = (unsigned short)f2bf(xr * c - xi * sn);
  unsigned short r1 = (unsigned short)f2bf(xr * sn + xi * c);
  *(unsigned*)(buf + base) = (unsigned)r0 | ((unsigned)r1 << 16);
}

// ------------------------------------------------------------------
// GEMM: C[m,n] = sum_k A[m,k]*B[n,k], A/B bf16 row-major [.][K].
// 128x128 tile, BK=64, global_load_lds staging (linear LDS, source-swizzled),
// swizzled ds_read_b128 -> conflict-free. 4 waves, 4x4 acc of 16x16x32.
#define MODE_Q   0
#define MODE_KV  1
#define MODE_OUT 2

template <int MODE>
__global__ __launch_bounds__(256) void gemm_bt(const bf16* __restrict__ A,
                                               const bf16* __restrict__ B,
                                               void* __restrict__ outp,
                                               void* __restrict__ outp2,
                                               int K, float scale) {
  __shared__ alignas(16) bf16 As[128 * 64];
  __shared__ alignas(16) bf16 Bs[128 * 64];

  const int tid = threadIdx.x;
  const int bm = blockIdx.x, bn = blockIdx.y;
  const int lane = tid & 63;
  const int wid = tid >> 6;
  const int wr = (wid >> 1) << 6;
  const int wc = (wid & 1) << 6;
  const int fr = lane & 15;
  const int g = lane >> 4;
  const int rg = g << 2;

  // staging geometry: linear LDS chunk L = i*256 + tid, row=L>>3, c=L&7.
  // source chunk pre-swizzled: sc = c ^ (row&7)  (row&7 == (tid>>3)&7 for all i)
  const int srow = tid >> 3;                       // + i*32
  const int sc = (tid & 7) ^ (srow & 7);
  const bf16* aptr = A + (size_t)(bm * 128 + srow) * K + sc * 8;
  const bf16* bptr = B + (size_t)(bn * 128 + srow) * K + sc * 8;
  bf16* ldsA = &As[(size_t)((tid & 192) << 3)];    // + i*256*8 elems
  bf16* ldsB = &Bs[(size_t)((tid & 192) << 3)];

  f4 acc[4][4] = {};

  const int nk = K >> 6;
  const size_t rstep = (size_t)32 * K;
  for (int kt = 0; kt < nk; ++kt) {
    const bf16* ak = aptr + kt * 64;
    const bf16* bk = bptr + kt * 64;
#pragma unroll
    for (int i = 0; i < 4; ++i) {
      gload16(ak + i * rstep, ldsA + i * 2048);
      gload16(bk + i * rstep, ldsB + i * 2048);
    }
    asm volatile("s_waitcnt vmcnt(0)" ::: "memory");
    __syncthreads();

#pragma unroll
    for (int ks = 0; ks < 2; ++ks) {
      s8v af[4], bfv[4];
      const int chc = (ks << 2) | g;
#pragma unroll
      for (int m = 0; m < 4; ++m) {
        const int row = wr + m * 16 + fr;
        af[m] = *(const s8v*)&As[row * 64 + ((chc ^ (row & 7)) << 3)];
      }
#pragma unroll
      for (int n = 0; n < 4; ++n) {
        const int row = wc + n * 16 + fr;
        bfv[n] = *(const s8v*)&Bs[row * 64 + ((chc ^ (row & 7)) << 3)];
      }
#pragma unroll
      for (int m = 0; m < 4; ++m)
#pragma unroll
        for (int n = 0; n < 4; ++n)
          acc[m][n] = __builtin_amdgcn_mfma_f32_16x16x32_bf16(af[m], bfv[n], acc[m][n], 0, 0, 0);
    }
    __syncthreads();
  }

  // epilogue: C row = token t (b = t>>10, s = t&1023); col = gcol
#pragma unroll
  for (int m = 0; m < 4; ++m) {
    const int gr0 = bm * 128 + wr + m * 16 + rg;   // rows gr0..gr0+3
    const int b = gr0 >> 10, s0 = gr0 & 1023;
#pragma unroll
    for (int n = 0; n < 4; ++n) {
      const int gcol = bn * 128 + wc + n * 16 + fr;
      if constexpr (MODE == MODE_OUT) {
#pragma unroll
        for (int j = 0; j < 4; ++j)
          ((float*)outp)[(size_t)(gr0 + j) * 4096 + gcol] = acc[m][n][j];
      } else if constexpr (MODE == MODE_Q) {
        const int h = gcol >> 7, d = gcol & 127;
#pragma unroll
        for (int j = 0; j < 4; ++j)
          ((bf16*)outp)[((((size_t)b * 32 + h) << 10) + s0 + j) * 128 + d] =
              __float2bfloat16(acc[m][n][j] * scale);
      } else {  // MODE_KV: cols 0..1023 = K proj, 1024..2047 = V proj
        const int hv = (gcol >> 7) & 7, d = gcol & 127;
        if (gcol < 1024) {
#pragma unroll
          for (int j = 0; j < 4; ++j)
            ((bf16*)outp)[(((size_t)b * 8 + hv) * 2048 + 1024 + s0 + j) * 128 + d] =
                __float2bfloat16(acc[m][n][j]);
        } else {
          s4v r = { f2bf(acc[m][n][0]), f2bf(acc[m][n][1]),
                    f2bf(acc[m][n][2]), f2bf(acc[m][n][3]) };
          *(s4v*)((bf16*)outp2 + (((size_t)b * 8 + hv) * 128 + d) * 2048 + 1024 + s0) = r;
        }
      }
    }
  }
}

// ------------------------------------------------------------------
// Flash attention, no mask. Q pre-scaled by 1/sqrt(128) (folded into Q GEMM).
// grid: (16 q-blocks, 128 b*h). 256 threads = 4 waves x 16 q-rows each.
__global__ __launch_bounds__(256) void attn_kernel(const bf16* __restrict__ Q,
                                                   const bf16* __restrict__ Kf,
                                                   const bf16* __restrict__ Vt,
                                                   bf16* __restrict__ O) {
  __shared__ alignas(16) bf16 Ks[64][136];   // keys x dim, +8 pad
  __shared__ alignas(16) bf16 Vs[128][72];   // dim  x keys, +8 pad
  __shared__ alignas(16) bf16 Ps[4][16][72]; // per-wave P tile

  const int tid = threadIdx.x;
  const int lane = tid & 63;
  const int w = tid >> 6;
  const int fr = lane & 15;
  const int fk = (lane >> 4) << 3;
  const int rg = (lane >> 4) << 2;

  const int qb = blockIdx.x;
  const int bh = blockIdx.y;
  const int b = bh >> 5, h = bh & 31;
  const int kv = h >> 2;

  const size_t qbase = (((size_t)b * 32 + h) << 10) * 128;
  const size_t kbase = (((size_t)b * 8 + kv) * 2048) * 128;
  const size_t vbase = (((size_t)b * 8 + kv) * 128) * 2048;

  const int qrow = qb * 64 + w * 16 + fr;
  s8v qa[4];
#pragma unroll
  for (int ks = 0; ks < 4; ++ks)
    qa[ks] = *(const s8v*)&Q[qbase + (size_t)qrow * 128 + ks * 32 + fk];

  f4 acco[8] = {};
  float mrun[4], lrun[4];
#pragma unroll
  for (int j = 0; j < 4; ++j) { mrun[j] = -1e30f; lrun[j] = 0.0f; }

  const int krow = tid >> 2, kcol = (tid & 3) << 5;   // 64x128 tile
  const int vrow = tid >> 1, vcol = (tid & 1) << 5;   // 128x64 tile

  for (int kb = 0; kb < 32; ++kb) {
    const u4v* kg = (const u4v*)&Kf[kbase + (size_t)(kb * 64 + krow) * 128 + kcol];
    u4v k0 = kg[0], k1 = kg[1], k2 = kg[2], k3 = kg[3];
    const u4v* vg = (const u4v*)&Vt[vbase + (size_t)vrow * 2048 + kb * 64 + vcol];
    u4v v0 = vg[0], v1 = vg[1], v2 = vg[2], v3 = vg[3];
    *(u4v*)&Ks[krow][kcol +  0] = k0;
    *(u4v*)&Ks[krow][kcol +  8] = k1;
    *(u4v*)&Ks[krow][kcol + 16] = k2;
    *(u4v*)&Ks[krow][kcol + 24] = k3;
    *(u4v*)&Vs[vrow][vcol +  0] = v0;
    *(u4v*)&Vs[vrow][vcol +  8] = v1;
    *(u4v*)&Vs[vrow][vcol + 16] = v2;
    *(u4v*)&Vs[vrow][vcol + 24] = v3;
    __syncthreads();

    f4 sc[4];
#pragma unroll
    for (int n = 0; n < 4; ++n) {
      f4 a = {0.f, 0.f, 0.f, 0.f};
#pragma unroll
      for (int ks = 0; ks < 4; ++ks) {
        s8v kfv = *(const s8v*)&Ks[n * 16 + fr][ks * 32 + fk];
        a = __builtin_amdgcn_mfma_f32_16x16x32_bf16(qa[ks], kfv, a, 0, 0, 0);
      }
      sc[n] = a;
    }

    float pm[4];
#pragma unroll
    for (int j = 0; j < 4; ++j)
      pm[j] = fmaxf(fmaxf(sc[0][j], sc[1][j]), fmaxf(sc[2][j], sc[3][j]));
#pragma unroll
    for (int j = 0; j < 4; ++j) {
      pm[j] = fmaxf(pm[j], __shfl_xor(pm[j], 1));
      pm[j] = fmaxf(pm[j], __shfl_xor(pm[j], 2));
      pm[j] = fmaxf(pm[j], __shfl_xor(pm[j], 4));
      pm[j] = fmaxf(pm[j], __shfl_xor(pm[j], 8));
    }
    float corr[4], rs[4];
#pragma unroll
    for (int j = 0; j < 4; ++j) {
      const float mn = fmaxf(mrun[j], pm[j]);
      corr[j] = __expf(mrun[j] - mn);
      mrun[j] = mn;
      float s0 = 0.f;
#pragma unroll
      for (int n = 0; n < 4; ++n) {
        const float p = __expf(sc[n][j] - mn);
        sc[n][j] = p;
        s0 += p;
      }
      rs[j] = s0;
    }
#pragma unroll
    for (int j = 0; j < 4; ++j) {
      rs[j] += __shfl_xor(rs[j], 1);
      rs[j] += __shfl_xor(rs[j], 2);
      rs[j] += __shfl_xor(rs[j], 4);
      rs[j] += __shfl_xor(rs[j], 8);
      lrun[j] = lrun[j] * corr[j] + rs[j];
    }
#pragma unroll
    for (int nt = 0; nt < 8; ++nt)
#pragma unroll
      for (int j = 0; j < 4; ++j) acco[nt][j] *= corr[j];

#pragma unroll
    for (int n = 0; n < 4; ++n)
#pragma unroll
      for (int j = 0; j < 4; ++j)
        Ps[w][rg + j][fr + n * 16] = __float2bfloat16(sc[n][j]);
    asm volatile("s_waitcnt lgkmcnt(0)" ::: "memory");

#pragma unroll
    for (int ks2 = 0; ks2 < 2; ++ks2) {
      s8v pf = *(const s8v*)&Ps[w][fr][ks2 * 32 + fk];
#pragma unroll
      for (int nt = 0; nt < 8; ++nt) {
        s8v vf = *(const s8v*)&Vs[nt * 16 + fr][ks2 * 32 + fk];
        acco[nt] = __builtin_amdgcn_mfma_f32_16x16x32_bf16(pf, vf, acco[nt], 0, 0, 0);
      }
    }
    __syncthreads();
  }

#pragma unroll
  for (int nt = 0; nt < 8; ++nt)
#pragma unroll
    for (int j = 0; j < 4; ++j) {
      const int r = qb * 64 + w * 16 + rg + j;
      const int dcol = nt * 16 + fr;
      const float v = acco[nt][j] / lrun[j];
      O[((size_t)b * 1024 + r) * 4096 + h * 128 + dcol] = __float2bfloat16(v);
    }
}

// ------------------------------------------------------------------
extern "C" void kernel_launch(void* const* d_in, const int* in_sizes, int n_in,
                              void* d_out, int out_size, void* d_ws, size_t ws_size,
                              hipStream_t stream) {
  const float* x  = (const float*)d_in[0];
  const float* fc = (const float*)d_in[1];
  const float* fs = (const float*)d_in[2];
  const float* ck = (const float*)d_in[3];
  const float* cv = (const float*)d_in[4];
  const float* wq = (const float*)d_in[5];
  const float* wk = (const float*)d_in[6];
  const float* wv = (const float*)d_in[7];
  const float* wo = (const float*)d_in[8];
  float* out = (float*)d_out;

  char* ws = (char*)d_ws;
  bf16* qr    = (bf16*)(ws);                     // [4][32][1024][128]  32 MiB
  bf16* kfull = (bf16*)(ws + (32u << 20));       // [4][8][2048][128]   16 MiB
  bf16* vt    = (bf16*)(ws + (48u << 20));       // [4][8][128][2048]   16 MiB
  bf16* xb    = (bf16*)(ws + (64u << 20));       // [4096][4096]        32 MiB
  bf16* attn  = xb;                              // aliases xb (dead by then)
  bf16* wqb   = (bf16*)(ws + (96u << 20));       // [4096][4096]        32 MiB
  bf16* wob   = wqb;                             // aliases wqb (dead by then)
  bf16* wkvb  = (bf16*)(ws + (128u << 20));      // [2048][4096]        16 MiB

  cvt_bf16<<<8192, 256, 0, stream>>>(x, xb);
  cvt_bf16<<<8192, 256, 0, stream>>>(wq, wqb);
  cvt_bf16<<<2048, 256, 0, stream>>>(wk, wkvb);
  cvt_bf16<<<2048, 256, 0, stream>>>(wv, wkvb + 4194304);
  cvt_cache_k<<<4096, 256, 0, stream>>>(ck, kfull);
  cvt_cache_v<<<4096, 256, 0, stream>>>(cv, vt);

  gemm_bt<MODE_Q><<<dim3(32, 32), 256, 0, stream>>>(
      xb, wqb, qr, nullptr, 4096, 0.08838834764831845f);
  gemm_bt<MODE_KV><<<dim3(32, 16), 256, 0, stream>>>(
      xb, wkvb, kfull, vt, 4096, 1.0f);

  cvt_bf16<<<8192, 256, 0, stream>>>(wo, wob);   // after Q-gemm: reuses wqb

  rope_kernel<<<32768, 256, 0, stream>>>(qr, fc, fs, 1024, 0);
  rope_kernel<<<8192, 256, 0, stream>>>(kfull, fc, fs, 2048, 1024);

  attn_kernel<<<dim3(16, 128), 256, 0, stream>>>(qr, kfull, vt, attn);

  gemm_bt<MODE_OUT><<<dim3(32, 32), 256, 0, stream>>>(
      attn, wob, out, nullptr, 4096, 1.0f);
}

// Round 3
// 755.687 us; speedup vs baseline: 1.6048x; 1.1924x over previous
//
#include <hip/hip_runtime.h>
#include <hip/hip_bf16.h>

using bf16 = __hip_bfloat16;
typedef __attribute__((ext_vector_type(4))) float f4;
typedef __attribute__((ext_vector_type(16))) float f16v;
typedef __attribute__((ext_vector_type(8))) short s8v;
typedef __attribute__((ext_vector_type(4))) short s4v;
typedef __attribute__((ext_vector_type(4))) unsigned int u4v;
typedef unsigned int u32;

__device__ __forceinline__ short f2bf(float x) {
  bf16 h = __float2bfloat16(x);
  return *reinterpret_cast<short*>(&h);
}

__device__ __forceinline__ u32 pkbf(float lo, float hi) {
  return (u32)(unsigned short)f2bf(lo) | ((u32)(unsigned short)f2bf(hi) << 16);
}

__device__ __forceinline__ void gload16(const bf16* g, bf16* l) {
  __builtin_amdgcn_global_load_lds(
      (const __attribute__((address_space(1))) u32*)g,
      (__attribute__((address_space(3))) u32*)l, 16, 0, 0);
}

// swap lanes 32..63 of a with lanes 0..31 of b (v_permlane32_swap_b32)
__device__ __forceinline__ void swp32(u32& a, u32& b, int h) {
#if __has_builtin(__builtin_amdgcn_permlane32_swap)
  typedef __attribute__((ext_vector_type(2))) int i2v;
  i2v r = __builtin_amdgcn_permlane32_swap((int)a, (int)b, false, false);
  a = (u32)r.x;
  b = (u32)r.y;
#else
  u32 as = (u32)__shfl_xor((int)a, 32), bs = (u32)__shfl_xor((int)b, 32);
  u32 an = h ? bs : a, bn = h ? b : as;
  a = an;
  b = bn;
#endif
}

// ------------------------------------------------------------------
// generic fp32 -> bf16, 8 elems/thread
__global__ __launch_bounds__(256) void cvt_bf16(const float* __restrict__ src,
                                                bf16* __restrict__ dst) {
  size_t e = ((size_t)blockIdx.x * 256 + threadIdx.x) << 3;
  f4 a = *(const f4*)(src + e);
  f4 b = *(const f4*)(src + e + 4);
  s8v r = { f2bf(a[0]), f2bf(a[1]), f2bf(a[2]), f2bf(a[3]),
            f2bf(b[0]), f2bf(b[1]), f2bf(b[2]), f2bf(b[3]) };
  *(s8v*)(dst + e) = r;
}

// cache_k [b][kv][p][d] f32 -> kfull [b][kv][p][d] bf16 (p < 1024)
__global__ __launch_bounds__(256) void cvt_cache_k(const float* __restrict__ src,
                                                   bf16* __restrict__ dst) {
  size_t e = ((size_t)blockIdx.x * 256 + threadIdx.x) << 2;
  f4 v = *(const f4*)(src + e);
  unsigned d = (unsigned)(e & 127u), p = (unsigned)((e >> 7) & 1023u), bk = (unsigned)(e >> 17);
  s4v r = { f2bf(v[0]), f2bf(v[1]), f2bf(v[2]), f2bf(v[3]) };
  *(s4v*)(dst + (((size_t)bk * 2048 + p) << 7) + d) = r;
}

// cache_v [b][kv][p][d] f32 -> vt [b][kv][d][p] bf16 (transposed, p < 1024)
__global__ __launch_bounds__(256) void cvt_cache_v(const float* __restrict__ src,
                                                   bf16* __restrict__ dst) {
  size_t e = ((size_t)blockIdx.x * 256 + threadIdx.x) << 2;
  unsigned p = (unsigned)(e & 1023u), d = (unsigned)((e >> 10) & 127u), bk = (unsigned)(e >> 17);
  const float* s = src + (((size_t)bk * 1024 + p) << 7) + d;
  s4v r = { f2bf(s[0]), f2bf(s[128]), f2bf(s[256]), f2bf(s[384]) };
  *(s4v*)(dst + (((size_t)bk * 128 + d) << 11) + p) = r;
}

// ------------------------------------------------------------------
// in-place RoPE on bf16 buffer laid out [hh][sstride][128]; rows soff+s
__global__ __launch_bounds__(256) void rope_kernel(bf16* __restrict__ buf,
                                                   const float* __restrict__ fc,
                                                   const float* __restrict__ fs,
                                                   int sstride, int soff) {
  size_t t = (size_t)blockIdx.x * 256 + threadIdx.x;
  unsigned ip = (unsigned)(t & 63u);
  unsigned s  = (unsigned)((t >> 6) & 1023u);
  unsigned hh = (unsigned)(t >> 16);
  size_t base = ((size_t)hh * sstride + soff + s) * 128 + 2 * ip;
  unsigned u = *(unsigned*)(buf + base);
  float xr = __uint_as_float(u << 16);
  float xi = __uint_as_float(u & 0xffff0000u);
  float c = fc[s * 64 + ip], sn = fs[s * 64 + ip];
  unsigned short r0 = (unsigned short)f2bf(xr * c - xi * sn);
  unsigned short r1 = (unsigned short)f2bf(xr * sn + xi * c);
  *(unsigned*)(buf + base) = (unsigned)r0 | ((unsigned)r1 << 16);
}

// ------------------------------------------------------------------
// GEMM: C[m,n] = sum_k A[m,k]*B[n,k], A/B bf16 row-major [.][K].
// 128x128 tile, BK=64, global_load_lds staging (linear LDS, source-swizzled),
// swizzled ds_read_b128 -> conflict-free. 4 waves, 4x4 acc of 16x16x32.
#define MODE_Q   0
#define MODE_KV  1
#define MODE_OUT 2

template <int MODE>
__global__ __launch_bounds__(256) void gemm_bt(const bf16* __restrict__ A,
                                               const bf16* __restrict__ B,
                                               void* __restrict__ outp,
                                               void* __restrict__ outp2,
                                               int K, float scale) {
  __shared__ alignas(16) bf16 As[128 * 64];
  __shared__ alignas(16) bf16 Bs[128 * 64];

  const int tid = threadIdx.x;
  const int bm = blockIdx.x, bn = blockIdx.y;
  const int lane = tid & 63;
  const int wid = tid >> 6;
  const int wr = (wid >> 1) << 6;
  const int wc = (wid & 1) << 6;
  const int fr = lane & 15;
  const int g = lane >> 4;
  const int rg = g << 2;

  const int srow = tid >> 3;
  const int sc = (tid & 7) ^ (srow & 7);
  const bf16* aptr = A + (size_t)(bm * 128 + srow) * K + sc * 8;
  const bf16* bptr = B + (size_t)(bn * 128 + srow) * K + sc * 8;
  bf16* ldsA = &As[(size_t)((tid & 192) << 3)];
  bf16* ldsB = &Bs[(size_t)((tid & 192) << 3)];

  f4 acc[4][4] = {};

  const int nk = K >> 6;
  const size_t rstep = (size_t)32 * K;
  for (int kt = 0; kt < nk; ++kt) {
    const bf16* ak = aptr + kt * 64;
    const bf16* bk = bptr + kt * 64;
#pragma unroll
    for (int i = 0; i < 4; ++i) {
      gload16(ak + i * rstep, ldsA + i * 2048);
      gload16(bk + i * rstep, ldsB + i * 2048);
    }
    asm volatile("s_waitcnt vmcnt(0)" ::: "memory");
    __syncthreads();

#pragma unroll
    for (int ks = 0; ks < 2; ++ks) {
      s8v af[4], bfv[4];
      const int chc = (ks << 2) | g;
#pragma unroll
      for (int m = 0; m < 4; ++m) {
        const int row = wr + m * 16 + fr;
        af[m] = *(const s8v*)&As[row * 64 + ((chc ^ (row & 7)) << 3)];
      }
#pragma unroll
      for (int n = 0; n < 4; ++n) {
        const int row = wc + n * 16 + fr;
        bfv[n] = *(const s8v*)&Bs[row * 64 + ((chc ^ (row & 7)) << 3)];
      }
#pragma unroll
      for (int m = 0; m < 4; ++m)
#pragma unroll
        for (int n = 0; n < 4; ++n)
          acc[m][n] = __builtin_amdgcn_mfma_f32_16x16x32_bf16(af[m], bfv[n], acc[m][n], 0, 0, 0);
    }
    __syncthreads();
  }

#pragma unroll
  for (int m = 0; m < 4; ++m) {
    const int gr0 = bm * 128 + wr + m * 16 + rg;
    const int b = gr0 >> 10, s0 = gr0 & 1023;
#pragma unroll
    for (int n = 0; n < 4; ++n) {
      const int gcol = bn * 128 + wc + n * 16 + fr;
      if constexpr (MODE == MODE_OUT) {
#pragma unroll
        for (int j = 0; j < 4; ++j)
          ((float*)outp)[(size_t)(gr0 + j) * 4096 + gcol] = acc[m][n][j];
      } else if constexpr (MODE == MODE_Q) {
        const int h = gcol >> 7, d = gcol & 127;
#pragma unroll
        for (int j = 0; j < 4; ++j)
          ((bf16*)outp)[((((size_t)b * 32 + h) << 10) + s0 + j) * 128 + d] =
              __float2bfloat16(acc[m][n][j] * scale);
      } else {  // MODE_KV
        const int hv = (gcol >> 7) & 7, d = gcol & 127;
        if (gcol < 1024) {
#pragma unroll
          for (int j = 0; j < 4; ++j)
            ((bf16*)outp)[(((size_t)b * 8 + hv) * 2048 + 1024 + s0 + j) * 128 + d] =
                __float2bfloat16(acc[m][n][j]);
        } else {
          s4v r = { f2bf(acc[m][n][0]), f2bf(acc[m][n][1]),
                    f2bf(acc[m][n][2]), f2bf(acc[m][n][3]) };
          *(s4v*)((bf16*)outp2 + (((size_t)b * 8 + hv) * 128 + d) * 2048 + 1024 + s0) = r;
        }
      }
    }
  }
}

// ------------------------------------------------------------------
// Flash attention, 8 waves x 32 q-rows, 32x32x16 MFMA, swapped QK^T and PV.
// Q pre-scaled by log2(e)/sqrt(128); softmax in exp2 domain, fully in-register.
// K LDS: [2 buf][2 half][64 k][64 d-elems] XOR-swizzled; V LDS: [2][128 d][64 k].
__global__ __launch_bounds__(512) void attn_kernel(const bf16* __restrict__ Q,
                                                   const bf16* __restrict__ Kf,
                                                   const bf16* __restrict__ Vt,
                                                   bf16* __restrict__ O) {
  __shared__ alignas(16) bf16 Kls[2][8192];
  __shared__ alignas(16) bf16 Vls[2][8192];

  const int tid = threadIdx.x;
  const int lane = tid & 63;
  const int w = tid >> 6;          // wave 0..7
  const int h = lane >> 5;         // half 0..1
  const int q31 = lane & 31;
  const int rx = q31 & 7;          // swizzle key for frag reads

  const int qb = blockIdx.x;       // 0..3
  const int bh = blockIdx.y;       // 0..127
  const int b = bh >> 5, hd = bh & 31;
  const int kv = hd >> 2;

  const size_t qbase = (((size_t)b * 32 + hd) << 10) * 128;
  const size_t kbase = (((size_t)b * 8 + kv) * 2048) * 128;
  const size_t vbase = (((size_t)b * 8 + kv) * 128) * 2048;

  // Q in registers: B-frag of swapped QK^T = Q[q31][c*16 + h*8 + j]
  const int qrow = qb * 256 + w * 32 + q31;
  s8v qf[8];
#pragma unroll
  for (int c = 0; c < 8; ++c)
    qf[c] = *(const s8v*)&Q[qbase + (size_t)qrow * 128 + c * 16 + h * 8];

  // staging geometry (global_load_lds, linear dest, pre-swizzled source)
  const int sr = tid >> 3;                 // 0..63
  const int swz8 = (((tid & 7) ^ (sr & 7)) << 3);
  const int wbase = w * 512;               // wave-uniform LDS base (elems)

  f16v oacc[4] = {};
  float mrun = -3e38f, lrun = 0.f;

  auto stage = [&](int kb, int bufi) {
    const bf16* ksrc = Kf + kbase + (size_t)(kb * 64 + sr) * 128 + swz8;
    gload16(ksrc,      &Kls[bufi][wbase]);
    gload16(ksrc + 64, &Kls[bufi][4096 + wbase]);
    const bf16* vsrc = Vt + vbase + (size_t)sr * 2048 + kb * 64 + swz8;
    gload16(vsrc,                      &Vls[bufi][wbase]);
    gload16(vsrc + (size_t)64 * 2048,  &Vls[bufi][4096 + wbase]);
  };

  stage(0, 0);
  asm volatile("s_waitcnt vmcnt(0)" ::: "memory");
  __syncthreads();

  for (int kb = 0; kb < 32; ++kb) {
    const int bufi = kb & 1;
    if (kb + 1 < 32) stage(kb + 1, bufi ^ 1);

    const bf16* KB = Kls[bufi];
    const bf16* VB = Vls[bufi];

    // S^T = K · Q^T : lane holds q=q31, k-rows (r&3)+8*(r>>2)+4h per subtile
    f16v sac[2] = {};
    __builtin_amdgcn_s_setprio(1);
#pragma unroll
    for (int c = 0; c < 8; ++c) {
      const int cc = 2 * c + h;
      const int cof = (cc >> 3) * 4096 + (((cc & 7) ^ rx) << 3);
      s8v k0 = *(const s8v*)&KB[cof + q31 * 64];
      s8v k1 = *(const s8v*)&KB[cof + (32 + q31) * 64];
      sac[0] = __builtin_amdgcn_mfma_f32_32x32x16_bf16(k0, qf[c], sac[0], 0, 0, 0);
      sac[1] = __builtin_amdgcn_mfma_f32_32x32x16_bf16(k1, qf[c], sac[1], 0, 0, 0);
    }
    __builtin_amdgcn_s_setprio(0);

    // online softmax (exp2 domain), lane-local + one lane^32 exchange
    float pm = -3e38f;
#pragma unroll
    for (int r = 0; r < 16; ++r) {
      pm = fmaxf(pm, sac[0][r]);
      pm = fmaxf(pm, sac[1][r]);
    }
    pm = fmaxf(pm, __shfl_xor(pm, 32));

    const bool skip = __all(pm <= mrun + 8.0f);   // defer-max (T13)
    if (!skip) {
      const float mnew = fmaxf(mrun, pm);
      const float corr = exp2f(mrun - mnew);
      mrun = mnew;
      lrun *= corr;
#pragma unroll
      for (int m = 0; m < 4; ++m)
#pragma unroll
        for (int r = 0; r < 16; ++r) oacc[m][r] *= corr;
    }
    float ls = 0.f;
#pragma unroll
    for (int s = 0; s < 2; ++s)
#pragma unroll
      for (int r = 0; r < 16; ++r) {
        const float p = exp2f(sac[s][r] - mrun);
        sac[s][r] = p;
        ls += p;
      }
    ls += __shfl_xor(ls, 32);
    lrun += ls;

    // P -> bf16 B-frags for PV, in-register via permlane32_swap (T12)
    s8v F[4];
#pragma unroll
    for (int s = 0; s < 2; ++s) {
      u32 W[8];
#pragma unroll
      for (int t = 0; t < 8; ++t) W[t] = pkbf(sac[s][2 * t], sac[s][2 * t + 1]);
      swp32(W[0], W[2], h); swp32(W[1], W[3], h);
      swp32(W[4], W[6], h); swp32(W[5], W[7], h);
      union { u32 u[4]; s8v v; } f0, f1;
      f0.u[0] = W[0]; f0.u[1] = W[1]; f0.u[2] = W[2]; f0.u[3] = W[3];
      f1.u[0] = W[4]; f1.u[1] = W[5]; f1.u[2] = W[6]; f1.u[3] = W[7];
      F[s * 2] = f0.v;
      F[s * 2 + 1] = f1.v;
    }

    // O^T += V^T · P^T : lane holds q=q31, d-rows per reg map
    __builtin_amdgcn_s_setprio(1);
#pragma unroll
    for (int ksg = 0; ksg < 4; ++ksg) {
      const int cc2 = 2 * ksg + h;
      const int vof = ((cc2 ^ rx) << 3);
#pragma unroll
      for (int m = 0; m < 4; ++m) {
        s8v vf = *(const s8v*)&VB[(m * 32 + q31) * 64 + vof];
        oacc[m] = __builtin_amdgcn_mfma_f32_32x32x16_bf16(vf, F[ksg], oacc[m], 0, 0, 0);
      }
    }
    __builtin_amdgcn_s_setprio(0);

    asm volatile("s_waitcnt vmcnt(0)" ::: "memory");
    __syncthreads();
  }

  // normalize + write O[b, qrow, hd*128 + d]
  const float inv = 1.f / lrun;
  bf16* orow = O + ((size_t)b * 1024 + qrow) * 4096 + hd * 128;
#pragma unroll
  for (int m = 0; m < 4; ++m)
#pragma unroll
    for (int r = 0; r < 16; r += 2) {
      const int d = m * 32 + (r & 3) + 8 * (r >> 2) + 4 * h;
      *(u32*)&orow[d] = pkbf(oacc[m][r] * inv, oacc[m][r + 1] * inv);
    }
}

// ------------------------------------------------------------------
extern "C" void kernel_launch(void* const* d_in, const int* in_sizes, int n_in,
                              void* d_out, int out_size, void* d_ws, size_t ws_size,
                              hipStream_t stream) {
  const float* x  = (const float*)d_in[0];
  const float* fc = (const float*)d_in[1];
  const float* fs = (const float*)d_in[2];
  const float* ck = (const float*)d_in[3];
  const float* cv = (const float*)d_in[4];
  const float* wq = (const float*)d_in[5];
  const float* wk = (const float*)d_in[6];
  const float* wv = (const float*)d_in[7];
  const float* wo = (const float*)d_in[8];
  float* out = (float*)d_out;

  char* ws = (char*)d_ws;
  bf16* qr    = (bf16*)(ws);                     // [4][32][1024][128]  32 MiB
  bf16* kfull = (bf16*)(ws + (32u << 20));       // [4][8][2048][128]   16 MiB
  bf16* vt    = (bf16*)(ws + (48u << 20));       // [4][8][128][2048]   16 MiB
  bf16* xb    = (bf16*)(ws + (64u << 20));       // [4096][4096]        32 MiB
  bf16* attn  = xb;                              // aliases xb (dead by then)
  bf16* wqb   = (bf16*)(ws + (96u << 20));       // [4096][4096]        32 MiB
  bf16* wob   = wqb;                             // aliases wqb (dead by then)
  bf16* wkvb  = (bf16*)(ws + (128u << 20));      // [2048][4096]        16 MiB

  cvt_bf16<<<8192, 256, 0, stream>>>(x, xb);
  cvt_bf16<<<8192, 256, 0, stream>>>(wq, wqb);
  cvt_bf16<<<2048, 256, 0, stream>>>(wk, wkvb);
  cvt_bf16<<<2048, 256, 0, stream>>>(wv, wkvb + 4194304);
  cvt_cache_k<<<4096, 256, 0, stream>>>(ck, kfull);
  cvt_cache_v<<<4096, 256, 0, stream>>>(cv, vt);

  // Q scale = 1/sqrt(128) * log2(e)  (softmax computed in exp2 domain)
  gemm_bt<MODE_Q><<<dim3(32, 32), 256, 0, stream>>>(
      xb, wqb, qr, nullptr, 4096, 0.1275174198520337f);
  gemm_bt<MODE_KV><<<dim3(32, 16), 256, 0, stream>>>(
      xb, wkvb, kfull, vt, 4096, 1.0f);

  cvt_bf16<<<8192, 256, 0, stream>>>(wo, wob);   // after Q-gemm: reuses wqb

  rope_kernel<<<32768, 256, 0, stream>>>(qr, fc, fs, 1024, 0);
  rope_kernel<<<8192, 256, 0, stream>>>(kfull, fc, fs, 2048, 1024);

  attn_kernel<<<dim3(4, 128), 512, 0, stream>>>(qr, kfull, vt, attn);

  gemm_bt<MODE_OUT><<<dim3(32, 32), 256, 0, stream>>>(
      attn, wob, out, nullptr, 4096, 1.0f);
}

// Round 4
// 667.476 us; speedup vs baseline: 1.8169x; 1.1322x over previous
//
#include <hip/hip_runtime.h>
#include <hip/hip_bf16.h>

using bf16 = __hip_bfloat16;
typedef __attribute__((ext_vector_type(4))) float f4;
typedef __attribute__((ext_vector_type(16))) float f16v;
typedef __attribute__((ext_vector_type(8))) short s8v;
typedef __attribute__((ext_vector_type(4))) short s4v;
typedef __attribute__((ext_vector_type(4))) unsigned int u4v;
typedef unsigned int u32;

__device__ __forceinline__ short f2bf(float x) {
  bf16 h = __float2bfloat16(x);
  return *reinterpret_cast<short*>(&h);
}

__device__ __forceinline__ u32 pkbf(float lo, float hi) {
  return (u32)(unsigned short)f2bf(lo) | ((u32)(unsigned short)f2bf(hi) << 16);
}

__device__ __forceinline__ void gload16(const bf16* g, bf16* l) {
  __builtin_amdgcn_global_load_lds(
      (const __attribute__((address_space(1))) u32*)g,
      (__attribute__((address_space(3))) u32*)l, 16, 0, 0);
}

// swap lanes 32..63 of a with lanes 0..31 of b (v_permlane32_swap_b32)
__device__ __forceinline__ void swp32(u32& a, u32& b, int h) {
#if __has_builtin(__builtin_amdgcn_permlane32_swap)
  typedef __attribute__((ext_vector_type(2))) int i2v;
  i2v r = __builtin_amdgcn_permlane32_swap((int)a, (int)b, false, false);
  a = (u32)r.x;
  b = (u32)r.y;
#else
  u32 as = (u32)__shfl_xor((int)a, 32), bs = (u32)__shfl_xor((int)b, 32);
  u32 an = h ? bs : a, bn = h ? b : as;
  a = an;
  b = bn;
#endif
}

// cross-half (lane ^ 32) max/sum without LDS traffic
__device__ __forceinline__ float xhalf_max(float x) {
#if __has_builtin(__builtin_amdgcn_permlane32_swap)
  typedef __attribute__((ext_vector_type(2))) int i2v;
  i2v r = __builtin_amdgcn_permlane32_swap(__float_as_int(x), __float_as_int(x),
                                           false, false);
  return fmaxf(__int_as_float(r.x), __int_as_float(r.y));
#else
  return fmaxf(x, __shfl_xor(x, 32));
#endif
}
__device__ __forceinline__ float xhalf_sum(float x) {
#if __has_builtin(__builtin_amdgcn_permlane32_swap)
  typedef __attribute__((ext_vector_type(2))) int i2v;
  i2v r = __builtin_amdgcn_permlane32_swap(__float_as_int(x), __float_as_int(x),
                                           false, false);
  return __int_as_float(r.x) + __int_as_float(r.y);
#else
  return x + __shfl_xor(x, 32);
#endif
}

// ------------------------------------------------------------------
// generic fp32 -> bf16, 8 elems/thread
__global__ __launch_bounds__(256) void cvt_bf16(const float* __restrict__ src,
                                                bf16* __restrict__ dst) {
  size_t e = ((size_t)blockIdx.x * 256 + threadIdx.x) << 3;
  f4 a = *(const f4*)(src + e);
  f4 b = *(const f4*)(src + e + 4);
  s8v r = { f2bf(a[0]), f2bf(a[1]), f2bf(a[2]), f2bf(a[3]),
            f2bf(b[0]), f2bf(b[1]), f2bf(b[2]), f2bf(b[3]) };
  *(s8v*)(dst + e) = r;
}

// cache_k [b][kv][p][d] f32 -> kfull [b][kv][p][d] bf16 (p < 1024)
__global__ __launch_bounds__(256) void cvt_cache_k(const float* __restrict__ src,
                                                   bf16* __restrict__ dst) {
  size_t e = ((size_t)blockIdx.x * 256 + threadIdx.x) << 2;
  f4 v = *(const f4*)(src + e);
  unsigned d = (unsigned)(e & 127u), p = (unsigned)((e >> 7) & 1023u), bk = (unsigned)(e >> 17);
  s4v r = { f2bf(v[0]), f2bf(v[1]), f2bf(v[2]), f2bf(v[3]) };
  *(s4v*)(dst + (((size_t)bk * 2048 + p) << 7) + d) = r;
}

// cache_v [b][kv][p][d] f32 -> vt [b][kv][d][p] bf16 (transposed, p < 1024)
__global__ __launch_bounds__(256) void cvt_cache_v(const float* __restrict__ src,
                                                   bf16* __restrict__ dst) {
  size_t e = ((size_t)blockIdx.x * 256 + threadIdx.x) << 2;
  unsigned p = (unsigned)(e & 1023u), d = (unsigned)((e >> 10) & 127u), bk = (unsigned)(e >> 17);
  const float* s = src + (((size_t)bk * 1024 + p) << 7) + d;
  s4v r = { f2bf(s[0]), f2bf(s[128]), f2bf(s[256]), f2bf(s[384]) };
  *(s4v*)(dst + (((size_t)bk * 128 + d) << 11) + p) = r;
}

// ------------------------------------------------------------------
// in-place RoPE on bf16 buffer laid out [hh][sstride][128]; rows soff+s
__global__ __launch_bounds__(256) void rope_kernel(bf16* __restrict__ buf,
                                                   const float* __restrict__ fc,
                                                   const float* __restrict__ fs,
                                                   int sstride, int soff) {
  size_t t = (size_t)blockIdx.x * 256 + threadIdx.x;
  unsigned ip = (unsigned)(t & 63u);
  unsigned s  = (unsigned)((t >> 6) & 1023u);
  unsigned hh = (unsigned)(t >> 16);
  size_t base = ((size_t)hh * sstride + soff + s) * 128 + 2 * ip;
  unsigned u = *(unsigned*)(buf + base);
  float xr = __uint_as_float(u << 16);
  float xi = __uint_as_float(u & 0xffff0000u);
  float c = fc[s * 64 + ip], sn = fs[s * 64 + ip];
  unsigned short r0 = (unsigned short)f2bf(xr * c - xi * sn);
  unsigned short r1 = (unsigned short)f2bf(xr * sn + xi * c);
  *(unsigned*)(buf + base) = (unsigned)r0 | ((unsigned)r1 << 16);
}

// ------------------------------------------------------------------
// 256x256-tile GEMM, BK=64, 8-phase schedule with counted vmcnt (T2+T3+T4+T5).
// C[m,n] = sum_k A[m,k]*B[n,k]; A,B bf16 row-major [.][K].
// 512 thr = 8 waves (2M x 4N); wave tile 128x64; acc 8x4 frags of 16x16x32.
// LDS (dynamic 128 KiB): A0,A1,B0,B1 tiles of 256x64, XOR-chunk-swizzled.
#define MODE_QKV 0
#define MODE_OUT 1

#define PHASE_TAIL(AC, BC, KS, MH)                                           \
  {                                                                          \
    s8v af[4], bv[4];                                                        \
    const int cofs = ((((KS) * 4) | g) ^ fx) << 3;                           \
    _Pragma("unroll") for (int mi = 0; mi < 4; ++mi)                         \
        af[mi] = *(const s8v*)&(AC)[aRowBase + ((MH)*4 + mi) * 1024 + cofs]; \
    _Pragma("unroll") for (int ni = 0; ni < 4; ++ni)                         \
        bv[ni] = *(const s8v*)&(BC)[bRowBase + ni * 1024 + cofs];            \
    __builtin_amdgcn_s_barrier();                                            \
    asm volatile("s_waitcnt lgkmcnt(0)" ::: "memory");                       \
    __builtin_amdgcn_s_setprio(1);                                           \
    _Pragma("unroll") for (int mi = 0; mi < 4; ++mi)                         \
      _Pragma("unroll") for (int ni = 0; ni < 4; ++ni)                       \
          acc[(MH)*4 + mi][ni] = __builtin_amdgcn_mfma_f32_16x16x32_bf16(    \
              af[mi], bv[ni], acc[(MH)*4 + mi][ni], 0, 0, 0);                \
    __builtin_amdgcn_s_setprio(0);                                           \
    __builtin_amdgcn_s_barrier();                                            \
  }

#define PHASE_HEAD(AC, BC)                                                   \
  {                                                                          \
    __builtin_amdgcn_s_barrier();                                            \
    s8v af[4], bv[4];                                                        \
    const int cofs = (g ^ fx) << 3;                                          \
    _Pragma("unroll") for (int mi = 0; mi < 4; ++mi)                         \
        af[mi] = *(const s8v*)&(AC)[aRowBase + mi * 1024 + cofs];            \
    _Pragma("unroll") for (int ni = 0; ni < 4; ++ni)                         \
        bv[ni] = *(const s8v*)&(BC)[bRowBase + ni * 1024 + cofs];            \
    asm volatile("s_waitcnt lgkmcnt(0)" ::: "memory");                       \
    __builtin_amdgcn_s_setprio(1);                                           \
    _Pragma("unroll") for (int mi = 0; mi < 4; ++mi)                         \
      _Pragma("unroll") for (int ni = 0; ni < 4; ++ni)                       \
          acc[mi][ni] = __builtin_amdgcn_mfma_f32_16x16x32_bf16(             \
              af[mi], bv[ni], acc[mi][ni], 0, 0, 0);                         \
    __builtin_amdgcn_s_setprio(0);                                           \
    __builtin_amdgcn_s_barrier();                                            \
  }

#define KTILE(AC, BC, PA, PB, NA, NB, PF)                                    \
  {                                                                          \
    if (PF) { gload16((NA), (PA)); gload16((NA) + rstep, (PA) + 4096); }     \
    if (PF) asm volatile("s_waitcnt vmcnt(2)" ::: "memory");                 \
    else    asm volatile("s_waitcnt vmcnt(0)" ::: "memory");                 \
    PHASE_HEAD(AC, BC)                                                       \
    if (PF) { gload16((NA) + 2 * rstep, (PA) + 8192);                        \
              gload16((NA) + 3 * rstep, (PA) + 12288); }                     \
    PHASE_TAIL(AC, BC, 0, 1)                                                 \
    if (PF) { gload16((NB), (PB)); gload16((NB) + rstep, (PB) + 4096); }     \
    PHASE_TAIL(AC, BC, 1, 0)                                                 \
    if (PF) { gload16((NB) + 2 * rstep, (PB) + 8192);                        \
              gload16((NB) + 3 * rstep, (PB) + 12288); }                     \
    PHASE_TAIL(AC, BC, 1, 1)                                                 \
  }

template <int MODE>
__global__ __launch_bounds__(512, 2) void gemm256(const bf16* __restrict__ A,
                                                  const bf16* __restrict__ B,
                                                  void* __restrict__ o1,
                                                  void* __restrict__ o2,
                                                  void* __restrict__ o3,
                                                  int K, float scale) {
  extern __shared__ bf16 smem[];
  bf16* A0 = smem;
  bf16* A1 = smem + 16384;
  bf16* B0 = smem + 32768;
  bf16* B1 = smem + 49152;

  const int tid = threadIdx.x;
  const int lane = tid & 63;
  const int wid = tid >> 6;
  const int wm = wid >> 2, wn = wid & 3;
  const int fr = lane & 15;
  const int g = lane >> 4;
  const int rg = g << 2;
  const int fx = lane & 7;

  // XCD-bijective block swizzle (nwg % 8 == 0 for all our grids)
  const int gy = gridDim.y;
  int lin = blockIdx.y * gridDim.x + blockIdx.x;
  const int qq = (gridDim.x * gy) >> 3;
  lin = (lin & 7) * qq + (lin >> 3);
  const int bm = lin / gy;
  const int bn = lin % gy;

  // staging: thread covers chunk (r0, c0) swizzled; gload i adds 64 rows
  const int r0 = tid >> 3;
  const int sc = (tid & 7) ^ (r0 & 7);
  const bf16* aptr = A + (size_t)(bm * 256 + r0) * K + sc * 8;
  const bf16* bptr = B + (size_t)(bn * 256 + r0) * K + sc * 8;
  const size_t rstep = (size_t)64 * K;
  const int wofs = (tid & 448) << 3;   // wave-uniform LDS base (elems)
  bf16* pA0 = A0 + wofs; bf16* pA1 = A1 + wofs;
  bf16* pB0 = B0 + wofs; bf16* pB1 = B1 + wofs;

  const int aRowBase = (wm * 128 + fr) * 64;
  const int bRowBase = (wn * 64 + fr) * 64;

  f4 acc[8][4] = {};

  // prologue: stage K-tile 0 into A0/B0 (8 loads in flight, no drain)
#pragma unroll
  for (int i = 0; i < 4; ++i) gload16(aptr + i * rstep, pA0 + i * 4096);
#pragma unroll
  for (int i = 0; i < 4; ++i) gload16(bptr + i * rstep, pB0 + i * 4096);

  const int nk = K >> 6;
  for (int kt = 0; kt < nk; kt += 2) {
    const bf16* na = aptr + (kt + 1) * 64;
    const bf16* nb = bptr + (kt + 1) * 64;
    KTILE(A0, B0, pA1, pB1, na, nb, true)
    const bool pf2 = (kt + 2 < nk);
    const bf16* na2 = aptr + (kt + 2) * 64;
    const bf16* nb2 = bptr + (kt + 2) * 64;
    KTILE(A1, B1, pA0, pB0, na2, nb2, pf2)
  }

  // epilogue
#pragma unroll
  for (int m = 0; m < 8; ++m) {
    const int grow0 = bm * 256 + wm * 128 + m * 16 + rg;
    const int b = grow0 >> 10, s0 = grow0 & 1023;
#pragma unroll
    for (int n = 0; n < 4; ++n) {
      const int gcol = bn * 256 + wn * 64 + n * 16 + fr;
      if constexpr (MODE == MODE_OUT) {
#pragma unroll
        for (int j = 0; j < 4; ++j)
          ((float*)o1)[(size_t)(grow0 + j) * 4096 + gcol] = acc[m][n][j];
      } else {
        if (gcol < 4096) {          // Q (scaled)
          const int h = gcol >> 7, d = gcol & 127;
#pragma unroll
          for (int j = 0; j < 4; ++j)
            ((bf16*)o1)[((((size_t)b * 32 + h) << 10) + s0 + j) * 128 + d] =
                __float2bfloat16(acc[m][n][j] * scale);
        } else if (gcol < 5120) {   // K
          const int c = gcol - 4096, hv = c >> 7, d = c & 127;
#pragma unroll
          for (int j = 0; j < 4; ++j)
            ((bf16*)o2)[(((size_t)b * 8 + hv) * 2048 + 1024 + s0 + j) * 128 + d] =
                __float2bfloat16(acc[m][n][j]);
        } else {                    // V (transposed write)
          const int c = gcol - 5120, hv = c >> 7, d = c & 127;
          s4v r = { f2bf(acc[m][n][0]), f2bf(acc[m][n][1]),
                    f2bf(acc[m][n][2]), f2bf(acc[m][n][3]) };
          *(s4v*)((bf16*)o3 + (((size_t)b * 8 + hv) * 128 + d) * 2048 + 1024 + s0) = r;
        }
      }
    }
  }
}

// ------------------------------------------------------------------
// Flash attention, 8 waves x 32 q-rows, 32x32x16 MFMA, swapped QK^T and PV.
// Q pre-scaled by log2(e)/sqrt(128); softmax in exp2 domain, fully in-register.
__global__ __launch_bounds__(512) void attn_kernel(const bf16* __restrict__ Q,
                                                   const bf16* __restrict__ Kf,
                                                   const bf16* __restrict__ Vt,
                                                   bf16* __restrict__ O) {
  __shared__ alignas(16) bf16 Kls[2][8192];
  __shared__ alignas(16) bf16 Vls[2][8192];

  const int tid = threadIdx.x;
  const int lane = tid & 63;
  const int w = tid >> 6;
  const int h = lane >> 5;
  const int q31 = lane & 31;
  const int rx = q31 & 7;

  const int qb = blockIdx.x;
  const int bh = blockIdx.y;
  const int b = bh >> 5, hd = bh & 31;
  const int kv = hd >> 2;

  const size_t qbase = (((size_t)b * 32 + hd) << 10) * 128;
  const size_t kbase = (((size_t)b * 8 + kv) * 2048) * 128;
  const size_t vbase = (((size_t)b * 8 + kv) * 128) * 2048;

  const int qrow = qb * 256 + w * 32 + q31;
  s8v qf[8];
#pragma unroll
  for (int c = 0; c < 8; ++c)
    qf[c] = *(const s8v*)&Q[qbase + (size_t)qrow * 128 + c * 16 + h * 8];

  const int sr = tid >> 3;
  const int swz8 = (((tid & 7) ^ (sr & 7)) << 3);
  const int wbase = w * 512;

  f16v oacc[4] = {};
  float mrun = -3e38f, lrun = 0.f;

  auto stage = [&](int kb, int bufi) {
    const bf16* ksrc = Kf + kbase + (size_t)(kb * 64 + sr) * 128 + swz8;
    gload16(ksrc,      &Kls[bufi][wbase]);
    gload16(ksrc + 64, &Kls[bufi][4096 + wbase]);
    const bf16* vsrc = Vt + vbase + (size_t)sr * 2048 + kb * 64 + swz8;
    gload16(vsrc,                      &Vls[bufi][wbase]);
    gload16(vsrc + (size_t)64 * 2048,  &Vls[bufi][4096 + wbase]);
  };

  stage(0, 0);
  asm volatile("s_waitcnt vmcnt(0)" ::: "memory");
  __syncthreads();

  for (int kb = 0; kb < 32; ++kb) {
    const int bufi = kb & 1;
    if (kb + 1 < 32) stage(kb + 1, bufi ^ 1);

    const bf16* KB = Kls[bufi];
    const bf16* VB = Vls[bufi];

    f16v sac[2] = {};
    __builtin_amdgcn_s_setprio(1);
#pragma unroll
    for (int c = 0; c < 8; ++c) {
      const int cc = 2 * c + h;
      const int cof = (cc >> 3) * 4096 + (((cc & 7) ^ rx) << 3);
      s8v k0 = *(const s8v*)&KB[cof + q31 * 64];
      s8v k1 = *(const s8v*)&KB[cof + (32 + q31) * 64];
      sac[0] = __builtin_amdgcn_mfma_f32_32x32x16_bf16(k0, qf[c], sac[0], 0, 0, 0);
      sac[1] = __builtin_amdgcn_mfma_f32_32x32x16_bf16(k1, qf[c], sac[1], 0, 0, 0);
    }
    __builtin_amdgcn_s_setprio(0);

    float pm = -3e38f;
#pragma unroll
    for (int r = 0; r < 16; ++r) {
      pm = fmaxf(pm, sac[0][r]);
      pm = fmaxf(pm, sac[1][r]);
    }
    pm = xhalf_max(pm);

    const bool skip = __all(pm <= mrun + 8.0f);   // defer-max (T13)
    if (!skip) {
      const float mnew = fmaxf(mrun, pm);
      const float corr = exp2f(mrun - mnew);
      mrun = mnew;
      lrun *= corr;
#pragma unroll
      for (int m = 0; m < 4; ++m)
#pragma unroll
        for (int r = 0; r < 16; ++r) oacc[m][r] *= corr;
    }
    float ls = 0.f;
#pragma unroll
    for (int s = 0; s < 2; ++s)
#pragma unroll
      for (int r = 0; r < 16; ++r) {
        const float p = exp2f(sac[s][r] - mrun);
        sac[s][r] = p;
        ls += p;
      }
    lrun += xhalf_sum(ls);

    // P -> bf16 B-frags for PV, in-register (T12)
    s8v F[4];
#pragma unroll
    for (int s = 0; s < 2; ++s) {
      u32 W[8];
#pragma unroll
      for (int t = 0; t < 8; ++t) W[t] = pkbf(sac[s][2 * t], sac[s][2 * t + 1]);
      swp32(W[0], W[2], h); swp32(W[1], W[3], h);
      swp32(W[4], W[6], h); swp32(W[5], W[7], h);
      union { u32 u[4]; s8v v; } f0, f1;
      f0.u[0] = W[0]; f0.u[1] = W[1]; f0.u[2] = W[2]; f0.u[3] = W[3];
      f1.u[0] = W[4]; f1.u[1] = W[5]; f1.u[2] = W[6]; f1.u[3] = W[7];
      F[s * 2] = f0.v;
      F[s * 2 + 1] = f1.v;
    }

    __builtin_amdgcn_s_setprio(1);
#pragma unroll
    for (int ksg = 0; ksg < 4; ++ksg) {
      const int cc2 = 2 * ksg + h;
      const int vof = ((cc2 ^ rx) << 3);
#pragma unroll
      for (int m = 0; m < 4; ++m) {
        s8v vf = *(const s8v*)&VB[(m * 32 + q31) * 64 + vof];
        oacc[m] = __builtin_amdgcn_mfma_f32_32x32x16_bf16(vf, F[ksg], oacc[m], 0, 0, 0);
      }
    }
    __builtin_amdgcn_s_setprio(0);

    asm volatile("s_waitcnt vmcnt(0)" ::: "memory");
    __syncthreads();
  }

  const float inv = 1.f / lrun;
  bf16* orow = O + ((size_t)b * 1024 + qrow) * 4096 + hd * 128;
#pragma unroll
  for (int m = 0; m < 4; ++m)
#pragma unroll
    for (int r = 0; r < 16; r += 2) {
      const int d = m * 32 + (r & 3) + 8 * (r >> 2) + 4 * h;
      *(u32*)&orow[d] = pkbf(oacc[m][r] * inv, oacc[m][r + 1] * inv);
    }
}

// ------------------------------------------------------------------
extern "C" void kernel_launch(void* const* d_in, const int* in_sizes, int n_in,
                              void* d_out, int out_size, void* d_ws, size_t ws_size,
                              hipStream_t stream) {
  const float* x  = (const float*)d_in[0];
  const float* fc = (const float*)d_in[1];
  const float* fs = (const float*)d_in[2];
  const float* ck = (const float*)d_in[3];
  const float* cv = (const float*)d_in[4];
  const float* wq = (const float*)d_in[5];
  const float* wk = (const float*)d_in[6];
  const float* wv = (const float*)d_in[7];
  const float* wo = (const float*)d_in[8];
  float* out = (float*)d_out;

  char* ws = (char*)d_ws;
  bf16* qr    = (bf16*)(ws);                     // [4][32][1024][128]  32 MiB
  bf16* kfull = (bf16*)(ws + (32u << 20));       // [4][8][2048][128]   16 MiB
  bf16* vt    = (bf16*)(ws + (48u << 20));       // [4][8][128][2048]   16 MiB
  bf16* xb    = (bf16*)(ws + (64u << 20));       // [4096][4096]        32 MiB
  bf16* attn  = xb;                              // aliases xb (dead by then)
  bf16* wqb   = (bf16*)(ws + (96u << 20));       // [4096][4096]        32 MiB
  bf16* wob   = wqb;                             // aliases wqb (dead by then)
  bf16* wkvb  = (bf16*)(ws + (128u << 20));      // [2048][4096] follows wqb contiguously

  hipFuncSetAttribute(reinterpret_cast<const void*>(&gemm256<MODE_QKV>),
                      hipFuncAttributeMaxDynamicSharedMemorySize, 131072);
  hipFuncSetAttribute(reinterpret_cast<const void*>(&gemm256<MODE_OUT>),
                      hipFuncAttributeMaxDynamicSharedMemorySize, 131072);

  cvt_bf16<<<8192, 256, 0, stream>>>(x, xb);
  cvt_bf16<<<8192, 256, 0, stream>>>(wq, wqb);
  cvt_bf16<<<2048, 256, 0, stream>>>(wk, wkvb);
  cvt_bf16<<<2048, 256, 0, stream>>>(wv, wkvb + 4194304);
  cvt_cache_k<<<4096, 256, 0, stream>>>(ck, kfull);
  cvt_cache_v<<<4096, 256, 0, stream>>>(cv, vt);

  // fused QKV projection: B = [wqb | wkvb] contiguous rows, N = 6144
  // Q scale = 1/sqrt(128) * log2(e)  (softmax computed in exp2 domain)
  gemm256<MODE_QKV><<<dim3(16, 24), 512, 131072, stream>>>(
      xb, wqb, qr, kfull, vt, 4096, 0.1275174198520337f);

  cvt_bf16<<<8192, 256, 0, stream>>>(wo, wob);   // after QKV gemm: reuses wqb

  rope_kernel<<<32768, 256, 0, stream>>>(qr, fc, fs, 1024, 0);
  rope_kernel<<<8192, 256, 0, stream>>>(kfull, fc, fs, 2048, 1024);

  attn_kernel<<<dim3(4, 128), 512, 0, stream>>>(qr, kfull, vt, attn);

  gemm256<MODE_OUT><<<dim3(16, 16), 512, 131072, stream>>>(
      attn, wob, out, nullptr, nullptr, 4096, 1.0f);
}